// Round 11
// baseline (349.253 us; speedup 1.0000x reference)
//
#include <hip/hip_runtime.h>

#define BD  32
#define CD  16
#define HD  256
#define WD  256
#define KD  4
#define OD  16
#define C4D 4

typedef __attribute__((ext_vector_type(8))) short short8v;   // 8 bf16 = 4 VGPR
typedef __attribute__((ext_vector_type(4))) float float4v;   // MFMA C/D

// Module-level scratch (no ws_size dependence). Fully overwritten every call.
__device__ float          g_partial[2048];                   // 4 partial sums per plane
__device__ unsigned short g_xbf[(size_t)BD * CD * HD * WD];  // bf16 copy of x (67 MB)
// Weight fragments in exact MFMA-B lane order: [b][prod(hi/lo)][kstep 5][lane 64][i 8]
__device__ unsigned short g_wfrag[BD * 2 * 5 * 64 * 8];

__device__ __forceinline__ unsigned short bf16_rne(float f) {
    unsigned u = __builtin_bit_cast(unsigned, f);
    u += 0x7FFFu + ((u >> 16) & 1u);
    return (unsigned short)(u >> 16);
}
__device__ __forceinline__ float bf16_to_f(unsigned short h) {
    unsigned u = ((unsigned)h) << 16;
    return __builtin_bit_cast(float, u);
}

// ---------------- Kernel 1: global average pool + bf16 emission ------------
__global__ void pool_kernel(const float* __restrict__ x) {
    const int plane = blockIdx.x >> 2;          // 0..511  (b*16+c)
    const int part  = blockIdx.x & 3;
    const size_t base = (size_t)plane * (HD * WD) + part * (HD * WD / 4);
    const float4* xp4 = reinterpret_cast<const float4*>(x + base);

    float4 v[16];
    #pragma unroll
    for (int i = 0; i < 16; ++i) v[i] = xp4[threadIdx.x + i * 256];

    float s = 0.f;
    #pragma unroll
    for (int i = 0; i < 16; ++i) {
        s += (v[i].x + v[i].y) + (v[i].z + v[i].w);
        ushort4 h;
        h.x = bf16_rne(v[i].x); h.y = bf16_rne(v[i].y);
        h.z = bf16_rne(v[i].z); h.w = bf16_rne(v[i].w);
        *reinterpret_cast<ushort4*>(&g_xbf[base + (size_t)(threadIdx.x + i * 256) * 4]) = h;
    }

    __shared__ float red[256];
    red[threadIdx.x] = s;
    __syncthreads();
    for (int off = 128; off > 0; off >>= 1) {
        if (threadIdx.x < off) red[threadIdx.x] += red[threadIdx.x + off];
        __syncthreads();
    }
    if (threadIdx.x == 0) g_partial[blockIdx.x] = red[0];
}

// ---------------- Kernel 2: attn MLP + softmax + bf16 weight fragments -----
// 128 blocks: 4 per sample. B-frag map (HW-verified R7): o=lane&15, kk=(lane>>4)*8+i.
__global__ void attn_agg_kernel(const float* __restrict__ w1, const float* __restrict__ b1,
                                const float* __restrict__ w2, const float* __restrict__ b2,
                                const float* __restrict__ weight) {
    const int b  = blockIdx.x >> 2;
    const int e0 = (blockIdx.x & 3) * 1280;

    float p[CD];
    #pragma unroll
    for (int c = 0; c < CD; ++c) {
        const int i0 = (b * CD + c) * 4;
        p[c] = (g_partial[i0] + g_partial[i0 + 1] + g_partial[i0 + 2] + g_partial[i0 + 3])
               * (1.f / (HD * WD));
    }

    float h[C4D];
    #pragma unroll
    for (int j = 0; j < C4D; ++j) {
        float s = b1[j];
        #pragma unroll
        for (int c = 0; c < CD; ++c) s = fmaf(p[c], w1[j * CD + c], s);
        h[j] = fmaxf(s, 0.f);
    }

    float lg[KD];
    float mx = -1e30f;
    #pragma unroll
    for (int k = 0; k < KD; ++k) {
        float s = b2[k];
        #pragma unroll
        for (int j = 0; j < C4D; ++j) s = fmaf(h[j], w2[k * C4D + j], s);
        lg[k] = s;
        mx = fmaxf(mx, s);
    }
    float se = 0.f;
    #pragma unroll
    for (int k = 0; k < KD; ++k) { lg[k] = expf(lg[k] - mx); se += lg[k]; }
    const float inv = 1.f / se;
    float at[KD];
    #pragma unroll
    for (int k = 0; k < KD; ++k) at[k] = lg[k] * inv;

    // e = ((prod*5 + s)*64 + lane)*8 + i ; kstep s covers taps {2s,2s+1} x 16c
    for (int e = e0 + threadIdx.x; e < e0 + 1280; e += 256) {
        const int prod = e / 2560;
        const int rem  = e % 2560;
        const int s    = rem / 512;
        const int lr   = rem % 512;
        const int lane = lr >> 3;
        const int i    = lr & 7;
        const int o    = lane & 15;
        const int kg   = lane >> 4;
        const int kk   = kg * 8 + i;
        const int tl   = kk >> 4;
        const int c    = kk & 15;
        const int tap  = 2 * s + tl;        // 0..9 (9 = padding)
        float v = 0.f;
        if (tap < 9) {
            #pragma unroll
            for (int k = 0; k < KD; ++k)
                v = fmaf(at[k], weight[((k * OD + o) * CD + c) * 9 + tap], v);
        }
        const unsigned short hi = bf16_rne(v);
        unsigned short val = hi;
        if (prod == 1) val = bf16_rne(v - bf16_to_f(hi));
        g_wfrag[b * 5120 + e] = val;
    }
}

// ---------------- Kernel 3: MFMA conv, 2-product (xhi*whi + xhi*wlo) -------
// Tile = 16 rows x 32 cols. LDS 18x34 records x 48 B = 29.4 KB -> 4 blocks/CU.
// Staging: single pass, 144 interior tasks (1 per thread), uint2 bf16 loads,
// register transpose, lane-ROTATED pixel order (pe=(p+j)&3) to break the
// R9 16-way ds_write_b128 bank conflict. 4 waves: wave w = col-half (w&1),
// rows 8*(w>>1)..+7; paired rows = 2 acc chains.
__global__ __launch_bounds__(256, 4)
void conv_kernel(float* __restrict__ out) {
    const int b  = blockIdx.y;
    const int tx = blockIdx.x & 7;        // 8 x 32-col strips
    const int ty = blockIdx.x >> 3;       // 16 x 16-row strips
    const int x0 = tx * 32, y0 = ty * 16;

    __shared__ unsigned short xs[18 * 34 * 24];   // 29,376 B

    const int tid = threadIdx.x;

    // ---- interior: 18 rows x 8 aligned 4-col groups = 144 tasks ----
    if (tid < 144) {
        const int r  = tid >> 3;          // 0..17
        const int j  = tid & 7;           // 0..7
        const int gy = y0 - 1 + r;
        const int gx = x0 + 4 * j;        // in [0,252], 8B-aligned in g_xbf
        const bool ok = (gy >= 0) && (gy < HD);
        uint2 v[16];
        #pragma unroll
        for (int c = 0; c < 16; ++c) {
            v[c] = make_uint2(0u, 0u);
            if (ok)
                v[c] = *reinterpret_cast<const uint2*>(
                    &g_xbf[((size_t)(b * CD + c) * HD + gy) * WD + gx]);
        }
        #pragma unroll
        for (int p = 0; p < 4; ++p) {
            const int pe = (p + j) & 3;   // lane-rotated pixel order (bank spread)
            unsigned d[8];
            #pragma unroll
            for (int i = 0; i < 8; ++i) {
                const unsigned a0 = (pe & 2) ? v[2 * i].y     : v[2 * i].x;
                const unsigned a1 = (pe & 2) ? v[2 * i + 1].y : v[2 * i + 1].x;
                d[i] = (pe & 1) ? ((a0 >> 16) | (a1 & 0xFFFF0000u))
                                : ((a0 & 0xFFFFu) | (a1 << 16));
            }
            const int e = r * 34 + 4 * j + 1 + pe;
            unsigned* dst = reinterpret_cast<unsigned*>(&xs[e * 24]);
            *reinterpret_cast<uint4*>(dst)     = make_uint4(d[0], d[1], d[2], d[3]);
            *reinterpret_cast<uint4*>(dst + 4) = make_uint4(d[4], d[5], d[6], d[7]);
        }
    } else if (tid < 180) {
        // ---- halo cols (local col 0 and 33): 36 records ----
        const int t   = tid - 144;
        const int r   = t >> 1;
        const int col = (t & 1) ? 33 : 0;
        const int gy  = y0 - 1 + r;
        const int gx  = x0 - 1 + col;
        const bool ok = (gy >= 0) && (gy < HD) && (gx >= 0) && (gx < WD);
        unsigned d[8];
        #pragma unroll
        for (int i = 0; i < 8; ++i) {
            unsigned u0 = 0, u1 = 0;
            if (ok) {
                u0 = g_xbf[((size_t)(b * CD + 2 * i)     * HD + gy) * WD + gx];
                u1 = g_xbf[((size_t)(b * CD + 2 * i + 1) * HD + gy) * WD + gx];
            }
            d[i] = u0 | (u1 << 16);
        }
        const int e = r * 34 + col;
        unsigned* dst = reinterpret_cast<unsigned*>(&xs[e * 24]);
        *reinterpret_cast<uint4*>(dst)     = make_uint4(d[0], d[1], d[2], d[3]);
        *reinterpret_cast<uint4*>(dst + 4) = make_uint4(d[4], d[5], d[6], d[7]);
    }

    const int lane = threadIdx.x & 63;
    const int wv   = threadIdx.x >> 6;

    // ---- weight fragments: registers, straight from g_wfrag ----
    short8v whi[5], wlo[5];
    {
        const unsigned short* wf = g_wfrag + b * 5120;
        #pragma unroll
        for (int s = 0; s < 5; ++s) {
            whi[s] = *(const short8v*)&wf[s * 512 + lane * 8];
            wlo[s] = *(const short8v*)&wf[2560 + s * 512 + lane * 8];
        }
    }

    // ---- per-lane A addressing (HW-verified R7): m=lane&15 pixel,
    //      kk=(lane>>4)*8+i; tl tap_local, chalf channel half ----
    const int m     = lane & 15;
    const int kg    = lane >> 4;
    const int tl    = kg >> 1;
    const int chalf = kg & 1;
    int aoff[5];
    #pragma unroll
    for (int s = 0; s < 5; ++s) {
        int tap = 2 * s + tl;
        if (tap > 8) tap = 8;             // pad-tap reads valid data; weights are 0
        const int dy = tap / 3 - 1, dx = tap % 3 - 1;
        aoff[s] = (dy * 34 + dx) * 24;    // u16 units
    }
    const int h       = wv & 1;           // col-half
    const int rb      = (wv >> 1) * 8;    // row base
    const int colbase = 1 + 16 * h + m;

    __syncthreads();

    // ---- compute: 8 rows per wave, in pairs (2 acc chains) ----
    #pragma unroll 1
    for (int q2 = 0; q2 < 4; ++q2) {
        const int qa = 2 * q2;
        const int pa = ((rb + qa + 1) * 34 + colbase) * 24 + chalf * 8;
        const int pb = pa + 34 * 24;
        float4v acca = {0.f, 0.f, 0.f, 0.f};
        float4v accb = {0.f, 0.f, 0.f, 0.f};
        #pragma unroll
        for (int s = 0; s < 5; ++s) {
            const short8v Aa = *(const short8v*)&xs[pa + aoff[s]];
            const short8v Ab = *(const short8v*)&xs[pb + aoff[s]];
            acca = __builtin_amdgcn_mfma_f32_16x16x32_bf16(Aa, whi[s], acca, 0, 0, 0);
            accb = __builtin_amdgcn_mfma_f32_16x16x32_bf16(Ab, whi[s], accb, 0, 0, 0);
            acca = __builtin_amdgcn_mfma_f32_16x16x32_bf16(Aa, wlo[s], acca, 0, 0, 0);
            accb = __builtin_amdgcn_mfma_f32_16x16x32_bf16(Ab, wlo[s], accb, 0, 0, 0);
        }
        // D (HW-verified R7): o = lane&15, pixel = kg*4 + reg -> float4 store
        const int o  = lane & 15;
        const int xc = x0 + 16 * h + kg * 4;
        const int y  = y0 + rb + qa;
        float4 va = make_float4(acca[0], acca[1], acca[2], acca[3]);
        float4 vb = make_float4(accb[0], accb[1], accb[2], accb[3]);
        *reinterpret_cast<float4*>(
            &out[((size_t)(b * OD + o) * HD + y) * WD + xc]) = va;
        *reinterpret_cast<float4*>(
            &out[((size_t)(b * OD + o) * HD + (y + 1)) * WD + xc]) = vb;
    }
}

extern "C" void kernel_launch(void* const* d_in, const int* in_sizes, int n_in,
                              void* d_out, int out_size, void* d_ws, size_t ws_size,
                              hipStream_t stream) {
    (void)in_sizes; (void)n_in; (void)out_size; (void)d_ws; (void)ws_size;
    const float* x      = (const float*)d_in[0];
    const float* weight = (const float*)d_in[1];
    const float* w1     = (const float*)d_in[2];
    const float* b1     = (const float*)d_in[3];
    const float* w2     = (const float*)d_in[4];
    const float* b2     = (const float*)d_in[5];
    float* out = (float*)d_out;

    pool_kernel<<<2048, 256, 0, stream>>>(x);
    attn_agg_kernel<<<128, 256, 0, stream>>>(w1, b1, w2, b2, weight);
    conv_kernel<<<dim3(128, 32), 256, 0, stream>>>(out);
}

// Round 12
// 311.384 us; speedup vs baseline: 1.1216x; 1.1216x over previous
//
#include <hip/hip_runtime.h>

#define BD  32
#define CD  16
#define HD  256
#define WD  256
#define KD  4
#define OD  16
#define C4D 4

typedef __attribute__((ext_vector_type(8))) short short8v;   // 8 bf16 = 4 VGPR
typedef __attribute__((ext_vector_type(4))) float float4v;   // MFMA C/D

// Module-level scratch (no ws_size dependence).
// g_xi: channel-interleaved bf16 x with 1-px zero frame: [b*2+chalf][y+1][x+1][ci0..7].
// Pad rows/cols are zero-initialized at module load and NEVER written -> stay zero.
__device__ float          g_partial[64 * 16 * 8];            // [bb][stripe][ci] partials
__device__ unsigned short g_xi[(size_t)64 * 258 * 258 * 8];  // 68 MB
// Weight fragments in exact MFMA-B lane order: [b][prod(hi/lo)][kstep 5][lane 64][i 8]
__device__ unsigned short g_wfrag[BD * 2 * 5 * 64 * 8];

__device__ __forceinline__ unsigned short bf16_rne(float f) {
    unsigned u = __builtin_bit_cast(unsigned, f);
    u += 0x7FFFu + ((u >> 16) & 1u);
    return (unsigned short)(u >> 16);
}
__device__ __forceinline__ float bf16_to_f(unsigned short h) {
    unsigned u = ((unsigned)h) << 16;
    return __builtin_bit_cast(float, u);
}

// ---------------- Kernel 1: pool + channel-interleave emission -------------
// 1024 blocks: bb = b*2+chalf (64) x 16 row-stripes. Thread = one column.
// Reads plane-coalesced (lane = col); writes contiguous 16B records.
__global__ __launch_bounds__(256)
void pool_kernel(const float* __restrict__ x) {
    const int bb     = blockIdx.x >> 4;        // 0..63
    const int stripe = blockIdx.x & 15;
    const int b      = bb >> 1;
    const int chalf  = bb & 1;
    const int tid    = threadIdx.x;

    float s8[8] = {0.f, 0.f, 0.f, 0.f, 0.f, 0.f, 0.f, 0.f};

    #pragma unroll 2
    for (int i = 0; i < 16; ++i) {
        const int y = stripe * 16 + i;
        const size_t prow = (size_t)y * WD + tid;
        float f[8];
        #pragma unroll
        for (int ci = 0; ci < 8; ++ci) {
            f[ci] = x[(size_t)(b * CD + chalf * 8 + ci) * (HD * WD) + prow];
            s8[ci] += f[ci];
        }
        const unsigned d0 = (unsigned)bf16_rne(f[0]) | ((unsigned)bf16_rne(f[1]) << 16);
        const unsigned d1 = (unsigned)bf16_rne(f[2]) | ((unsigned)bf16_rne(f[3]) << 16);
        const unsigned d2 = (unsigned)bf16_rne(f[4]) | ((unsigned)bf16_rne(f[5]) << 16);
        const unsigned d3 = (unsigned)bf16_rne(f[6]) | ((unsigned)bf16_rne(f[7]) << 16);
        *reinterpret_cast<uint4*>(
            &g_xi[(((size_t)bb * 258 + (y + 1)) * 258 + (tid + 1)) * 8]) =
            make_uint4(d0, d1, d2, d3);
    }

    // wave shuffle-reduce, then cross-wave via tiny LDS
    #pragma unroll
    for (int ci = 0; ci < 8; ++ci) {
        float v = s8[ci];
        #pragma unroll
        for (int off = 32; off > 0; off >>= 1) v += __shfl_down(v, off, 64);
        s8[ci] = v;
    }
    __shared__ float ws[4][8];
    const int lane = tid & 63, wv = tid >> 6;
    if (lane == 0) {
        #pragma unroll
        for (int ci = 0; ci < 8; ++ci) ws[wv][ci] = s8[ci];
    }
    __syncthreads();
    if (tid < 8)
        g_partial[(bb * 16 + stripe) * 8 + tid] =
            ws[0][tid] + ws[1][tid] + ws[2][tid] + ws[3][tid];
}

// ---------------- Kernel 2: attn MLP + softmax + bf16 weight fragments -----
// 128 blocks: 4 per sample. B-frag map (HW-verified R7): o=lane&15, kk=(lane>>4)*8+i.
__global__ void attn_agg_kernel(const float* __restrict__ w1, const float* __restrict__ b1,
                                const float* __restrict__ w2, const float* __restrict__ b2,
                                const float* __restrict__ weight) {
    const int b  = blockIdx.x >> 2;
    const int e0 = (blockIdx.x & 3) * 1280;

    float p[CD];
    #pragma unroll
    for (int c = 0; c < CD; ++c) {
        const int bb = b * 2 + (c >> 3);
        const int ci = c & 7;
        float s = 0.f;
        #pragma unroll
        for (int st = 0; st < 16; ++st) s += g_partial[(bb * 16 + st) * 8 + ci];
        p[c] = s * (1.f / (HD * WD));
    }

    float h[C4D];
    #pragma unroll
    for (int j = 0; j < C4D; ++j) {
        float s = b1[j];
        #pragma unroll
        for (int c = 0; c < CD; ++c) s = fmaf(p[c], w1[j * CD + c], s);
        h[j] = fmaxf(s, 0.f);
    }

    float lg[KD];
    float mx = -1e30f;
    #pragma unroll
    for (int k = 0; k < KD; ++k) {
        float s = b2[k];
        #pragma unroll
        for (int j = 0; j < C4D; ++j) s = fmaf(h[j], w2[k * C4D + j], s);
        lg[k] = s;
        mx = fmaxf(mx, s);
    }
    float se = 0.f;
    #pragma unroll
    for (int k = 0; k < KD; ++k) { lg[k] = expf(lg[k] - mx); se += lg[k]; }
    const float inv = 1.f / se;
    float at[KD];
    #pragma unroll
    for (int k = 0; k < KD; ++k) at[k] = lg[k] * inv;

    // e = ((prod*5 + s)*64 + lane)*8 + i ; kstep s covers taps {2s,2s+1} x 16c
    for (int e = e0 + threadIdx.x; e < e0 + 1280; e += 256) {
        const int prod = e / 2560;
        const int rem  = e % 2560;
        const int s    = rem / 512;
        const int lr   = rem % 512;
        const int lane = lr >> 3;
        const int i    = lr & 7;
        const int o    = lane & 15;
        const int kg   = lane >> 4;
        const int kk   = kg * 8 + i;
        const int tl   = kk >> 4;
        const int c    = kk & 15;
        const int tap  = 2 * s + tl;        // 0..9 (9 = padding)
        float v = 0.f;
        if (tap < 9) {
            #pragma unroll
            for (int k = 0; k < KD; ++k)
                v = fmaf(at[k], weight[((k * OD + o) * CD + c) * 9 + tap], v);
        }
        const unsigned short hi = bf16_rne(v);
        unsigned short val = hi;
        if (prod == 1) val = bf16_rne(v - bf16_to_f(hi));
        g_wfrag[b * 5120 + e] = val;
    }
}

// ---------------- Kernel 3: MFMA conv — NO LDS, NO barriers ----------------
// Tile = 16 rows x 64 cols; wave w owns cols 16w..16w+15, all 16 rows.
// A-fragment per lane = ONE dwordx4 from g_xi (8 channels of one pixel);
// lanes 0-15 read 256 B contiguous. Zero-padded frame -> no edge branches.
// Per block: 640 loads + 640 MFMAs, pure TLP (no __syncthreads anywhere).
__global__ __launch_bounds__(256, 4)
void conv_kernel(float* __restrict__ out) {
    const int b  = blockIdx.y;
    const int tx = blockIdx.x & 3;        // 4 x 64-col strips
    const int ty = blockIdx.x >> 2;       // 16 x 16-row strips
    const int x0 = tx * 64, y0 = ty * 16;
    const int lane = threadIdx.x & 63;
    const int wv   = threadIdx.x >> 6;

    // ---- weight fragments: registers, straight from g_wfrag ----
    short8v whi[5], wlo[5];
    {
        const unsigned short* wf = g_wfrag + b * 5120;
        #pragma unroll
        for (int s = 0; s < 5; ++s) {
            whi[s] = *(const short8v*)&wf[s * 512 + lane * 8];
            wlo[s] = *(const short8v*)&wf[2560 + s * 512 + lane * 8];
        }
    }

    // ---- per-lane A addressing (HW-verified R7): m=lane&15 pixel,
    //      kk=(lane>>4)*8+i; tl=kg>>1 tap_local, chalf=kg&1, ci=i ----
    const int m     = lane & 15;
    const int kg    = lane >> 4;
    const int tl    = kg >> 1;
    const int chalf = kg & 1;
    const int bb    = b * 2 + chalf;
    const int col   = x0 + wv * 16 + m;
    const unsigned short* bptr =
        g_xi + (((size_t)bb * 258 + (y0 + 1)) * 258 + (col + 1)) * 8;

    int aoff[5];
    #pragma unroll
    for (int s = 0; s < 5; ++s) {
        int tap = 2 * s + tl;
        if (tap > 8) tap = 8;             // pad-kstep: weights are 0
        const int dy = tap / 3 - 1, dx = tap % 3 - 1;
        aoff[s] = (dy * 258 + dx) * 8;    // u16 units (may be negative; base>=2072)
    }

    const int o  = lane & 15;
    const int xc = x0 + wv * 16 + kg * 4;

    // ---- compute: 8 row-pairs, 2 acc chains ----
    #pragma unroll 1
    for (int q2 = 0; q2 < 8; ++q2) {
        const int qa = 2 * q2;
        const unsigned short* pa = bptr + qa * (258 * 8);
        const unsigned short* pb = pa + 258 * 8;
        float4v acca = {0.f, 0.f, 0.f, 0.f};
        float4v accb = {0.f, 0.f, 0.f, 0.f};
        #pragma unroll
        for (int s = 0; s < 5; ++s) {
            const short8v Aa = *(const short8v*)(pa + aoff[s]);
            const short8v Ab = *(const short8v*)(pb + aoff[s]);
            acca = __builtin_amdgcn_mfma_f32_16x16x32_bf16(Aa, whi[s], acca, 0, 0, 0);
            accb = __builtin_amdgcn_mfma_f32_16x16x32_bf16(Ab, whi[s], accb, 0, 0, 0);
            acca = __builtin_amdgcn_mfma_f32_16x16x32_bf16(Aa, wlo[s], acca, 0, 0, 0);
            accb = __builtin_amdgcn_mfma_f32_16x16x32_bf16(Ab, wlo[s], accb, 0, 0, 0);
        }
        // D (HW-verified R7): o = lane&15, pixel = kg*4 + reg -> float4 store
        const int y = y0 + qa;
        float4 va = make_float4(acca[0], acca[1], acca[2], acca[3]);
        float4 vb = make_float4(accb[0], accb[1], accb[2], accb[3]);
        *reinterpret_cast<float4*>(
            &out[((size_t)(b * OD + o) * HD + y) * WD + xc]) = va;
        *reinterpret_cast<float4*>(
            &out[((size_t)(b * OD + o) * HD + (y + 1)) * WD + xc]) = vb;
    }
}

extern "C" void kernel_launch(void* const* d_in, const int* in_sizes, int n_in,
                              void* d_out, int out_size, void* d_ws, size_t ws_size,
                              hipStream_t stream) {
    (void)in_sizes; (void)n_in; (void)out_size; (void)d_ws; (void)ws_size;
    const float* x      = (const float*)d_in[0];
    const float* weight = (const float*)d_in[1];
    const float* w1     = (const float*)d_in[2];
    const float* b1     = (const float*)d_in[3];
    const float* w2     = (const float*)d_in[4];
    const float* b2     = (const float*)d_in[5];
    float* out = (float*)d_out;

    pool_kernel<<<1024, 256, 0, stream>>>(x);
    attn_agg_kernel<<<128, 256, 0, stream>>>(w1, b1, w2, b2, weight);
    conv_kernel<<<dim3(64, 32), 256, 0, stream>>>(out);
}